// Round 12
// baseline (167.301 us; speedup 1.0000x reference)
//
#include <hip/hip_runtime.h>
#include <cstdint>

// ---------------------------------------------------------------------------
// PointCLIP forward on MI355X. GEMMs in bf16 MFMA (fp32 accum), rest fp32.
// Weights pre-converted to bf16 once; XCD-affinity keeps per-XCD GEMM working
// sets inside the private 4MB L2 (per-XCD share of A+B must fit — r10 lesson).
// GEMM3 fuses bias+relu+0.6x into its epilogue (bf16 out). BN stats via
// atomic-free slab trees; final slab sum inlined into bn_apply.
// Dims fixed per reference: B=512, V=10, D=1024, C=100, P=4.
// ---------------------------------------------------------------------------

typedef unsigned short u16;
typedef __attribute__((ext_vector_type(8))) short bf8v;   // 8 bf16 (4 VGPR)
typedef __attribute__((ext_vector_type(4))) float f4v;    // 4 f32 acc

__device__ __forceinline__ float4 ld4(const float* p){ return *reinterpret_cast<const float4*>(p); }
__device__ __forceinline__ void st4(float* p, float4 v){ *reinterpret_cast<float4*>(p) = v; }
__device__ __forceinline__ u16 f2bf(float x){            // RNE fp32 -> bf16
  uint32_t u = __float_as_uint(x);
  return (u16)((u + 0x7FFFu + ((u>>16)&1u)) >> 16);
}
__device__ __forceinline__ float bf2f(u16 h){ return __uint_as_float(((uint32_t)h)<<16); }
__device__ __forceinline__ uint32_t pk(float a, float b){
  return (uint32_t)f2bf(a) | ((uint32_t)f2bf(b)<<16);
}
__device__ __forceinline__ void glds16(const u16* g, u16* l){
  __builtin_amdgcn_global_load_lds(
      (const __attribute__((address_space(1))) unsigned int*)g,
      (__attribute__((address_space(3))) unsigned int*)l, 16, 0, 0);
}

// ---- block-index remap: 0 plain 3D, 1 z-affinity, 2 n-affinity ------------
__device__ __forceinline__ void remap(int map, int NBX, int NBY,
                                      int& bx, int& by, int& bz)
{
  if (map == 0){ bx = blockIdx.x; by = blockIdx.y; bz = blockIdx.z; return; }
  const int i = blockIdx.x, xcd = i & 7, j = i >> 3;
  if (map == 1){
    const int mnC = NBX*NBY;
    const int zPer = (gridDim.x >> 3) / mnC;
    bz = xcd*zPer + j/mnC;
    const int mn = j % mnC; bx = mn % NBX; by = mn / NBX;
  } else {
    const int nbxPer = NBX >> 3;
    bx = xcd*nbxPer + j % nbxPer; by = j / nbxPer; bz = 0;
  }
}

// ---------------- bf16 NT MFMA GEMM, 64x128 tile ---------------------------
// A: (M,K) bf16 row-major. B: (N,K) bf16 row-major. C fp32 ldc, split-K slab.
// If OB != nullptr: instead write bf16 OB[row][col] = 0.6*relu(acc+bv2[col]).
__global__ __launch_bounds__(256,4)
void gemm_bf16_nt(const u16* __restrict__ A, const u16* __restrict__ B,
                  float* __restrict__ C, int lda, int ldb, int ldc,
                  int kLen, long strideCz, int map, int NBX, int NBY,
                  u16* __restrict__ OB, const float* __restrict__ bv2r)
{
  __shared__ u16 As0[2048], Bs0[4096], As1[2048], Bs1[4096];
  const int tid = threadIdx.x, lane = tid & 63, w = tid >> 6;
  int bx, by, bz; remap(map, NBX, NBY, bx, by, bz);

  const long bm = (long)by*64, bn = (long)bx*128;
  const long kz = (long)bz*kLen;
  C += (long)bz*strideCz;

  const int srow  = lane>>2;
  const int sslot = (lane&3) ^ ((lane>>3)&3);
  const u16* Ag = A + (bm + w*16 + srow)*(long)lda + kz + sslot*8;
  const u16* Bg = B + (bn + w*32 + srow)*(long)ldb + kz + sslot*8;
  const long b16 = 16L*ldb;
  const int woffA = w*512, woffB = w*1024;

  const int fr = lane & 15;
  const int rslot = ((lane>>4) ^ ((lane>>1)&3))*16;
  const int wr = (w>>1)*32, wc = (w&1)*64;

  const f4v zero = {0.f,0.f,0.f,0.f};
  f4v acc[2][4];
  #pragma unroll
  for (int i2=0;i2<2;i2++)
    #pragma unroll
    for (int j2=0;j2<4;j2++) acc[i2][j2]=zero;

  auto STAGE = [&](u16* Al, u16* Bl, int kt){
    glds16(Ag + kt,       Al + woffA);
    glds16(Bg + kt,       Bl + woffB);
    glds16(Bg + kt + b16, Bl + woffB + 512);
  };
  auto COMPUTE = [&](const u16* Asb, const u16* Bsb){
    bf8v af[2], bf[4];
    #pragma unroll
    for (int mi=0; mi<2; ++mi)
      af[mi] = *(const bf8v*)((const char*)Asb + (wr+mi*16+fr)*64 + rslot);
    #pragma unroll
    for (int nj=0; nj<4; ++nj)
      bf[nj] = *(const bf8v*)((const char*)Bsb + (wc+nj*16+fr)*64 + rslot);
    #pragma unroll
    for (int mi=0; mi<2; ++mi)
      #pragma unroll
      for (int nj=0; nj<4; ++nj)
        acc[mi][nj] = __builtin_amdgcn_mfma_f32_16x16x32_bf16(af[mi], bf[nj], acc[mi][nj], 0,0,0);
  };

  STAGE(As0, Bs0, 0);
  __syncthreads();
  int kt = 32;
  for (; kt < kLen - 32; kt += 64){
    STAGE(As1, Bs1, kt);
    COMPUTE(As0, Bs0);
    __syncthreads();
    STAGE(As0, Bs0, kt + 32);
    COMPUTE(As1, Bs1);
    __syncthreads();
  }
  STAGE(As1, Bs1, kt);
  COMPUTE(As0, Bs0);
  __syncthreads();
  COMPUTE(As1, Bs1);

  const int orow = (lane>>4)*4;
  if (OB){
    float bv[4];
    #pragma unroll
    for (int nj=0;nj<4;++nj) bv[nj] = bv2r[bn + wc + fr + nj*16];
    #pragma unroll
    for (int mi=0;mi<2;++mi){
      #pragma unroll
      for (int q=0;q<4;++q){
        const long row = bm + wr + mi*16 + orow + q;
        u16* Orow = OB + row*(long)ldc + bn + wc + fr;
        #pragma unroll
        for (int nj=0;nj<4;++nj)
          Orow[nj*16] = f2bf(0.6f*fmaxf(acc[mi][nj][q] + bv[nj], 0.f));
      }
    }
  } else {
    #pragma unroll
    for (int mi=0;mi<2;++mi){
      #pragma unroll
      for (int q=0;q<4;++q){
        const long row = bm + wr + mi*16 + orow + q;
        float* Crow = C + row*(long)ldc + bn + wc + fr;
        #pragma unroll
        for (int nj=0;nj<4;++nj) Crow[nj*16] = acc[mi][nj][q];
      }
    }
  }
}

// --------------- fp32 -> bf16 weight convert (Wg + Wv1 in one pass) --------
__global__ __launch_bounds__(256)
void cvt_w(const float* __restrict__ Wg, const float* __restrict__ Wv1,
           u16* __restrict__ WB, u16* __restrict__ W1b)
{
  const long NG = 1310720;
  const long NT = NG + 131072;
  for (long i = (long)blockIdx.x*256 + threadIdx.x; i < NT; i += (long)gridDim.x*256){
    const float* src; u16* dst; long k;
    if (i < NG){ src = Wg; dst = WB; k = i; }
    else       { src = Wv1; dst = W1b; k = i - NG; }
    const float4 a = ld4(&src[k*8]), b = ld4(&src[k*8+4]);
    uint4 o;
    o.x = pk(a.x,a.y); o.y = pk(a.z,a.w);
    o.z = pk(b.x,b.y); o.w = pk(b.z,b.w);
    *reinterpret_cast<uint4*>(&dst[k*8]) = o;
  }
}

__global__ __launch_bounds__(256)
void cvt_bf16(const float* __restrict__ in, u16* __restrict__ out, long n8)
{
  for (long i = (long)blockIdx.x*256 + threadIdx.x; i < n8; i += (long)gridDim.x*256){
    const float4 a = ld4(&in[i*8]), b = ld4(&in[i*8+4]);
    uint4 o;
    o.x = pk(a.x,a.y); o.y = pk(a.z,a.w);
    o.z = pk(b.x,b.y); o.w = pk(b.z,b.w);
    *reinterpret_cast<uint4*>(&out[i*8]) = o;
  }
}

// --------- split-K reduce + per-row BN stats partials (block = row) --------
__global__ __launch_bounds__(256)
void reduce_f32_stats(const float* __restrict__ P, int S, int MN,
                      const float* __restrict__ bias, float* __restrict__ out,
                      float* __restrict__ part)
{
  const int b = blockIdx.x, t = threadIdx.x;
  const long i = (long)b*1024 + t*4;
  float4 s = ld4(&P[i]);
  for (int z=1; z<S; ++z){
    const float4 v = ld4(&P[(long)z*MN + i]);
    s.x+=v.x; s.y+=v.y; s.z+=v.z; s.w+=v.w;
  }
  const float4 bb = ld4(&bias[t*4]);
  s.x+=bb.x; s.y+=bb.y; s.z+=bb.z; s.w+=bb.w;
  st4(&out[i], s);
  float* p = part + (long)b*2048;
  st4(&p[t*4], s);
  st4(&p[1024+t*4], make_float4(s.x*s.x, s.y*s.y, s.z*s.z, s.w*s.w));
}

__global__ __launch_bounds__(256)
void reduce_bf16(const float* __restrict__ P, int S, int MN,
                 const float* __restrict__ bias, u16* __restrict__ out)
{
  const long i = ((long)blockIdx.x*256 + threadIdx.x)*4;
  float4 s = ld4(&P[i]);
  for (int z=1; z<S; ++z){
    const float4 v = ld4(&P[(long)z*MN + i]);
    s.x+=v.x; s.y+=v.y; s.z+=v.z; s.w+=v.w;
  }
  const float4 b = ld4(&bias[(int)(i & 1023)]);
  s.x = fmaxf(s.x+b.x,0.f); s.y = fmaxf(s.y+b.y,0.f);
  s.z = fmaxf(s.z+b.z,0.f); s.w = fmaxf(s.w+b.w,0.f);
  uint2 o; o.x = pk(s.x,s.y); o.y = pk(s.z,s.w);
  *reinterpret_cast<uint2*>(&out[i]) = o;
}

// --------------- column stats: multi-stage tree, NO atomics ----------------
__global__ __launch_bounds__(256)
void colstats_p1(const float* __restrict__ X, int rpb, const float* __restrict__ fr,
                 float* __restrict__ part)
{
  const int c = threadIdx.x*4;
  const long r0 = (long)blockIdx.x*rpb;
  float4 s = make_float4(0,0,0,0), q = make_float4(0,0,0,0);
  for (int rr=0; rr<rpb; ++rr){
    const long r = r0+rr;
    float4 x = ld4(&X[r*1024 + c]);
    if (fr){ const float f = fr[(int)(r%10)]; x.x*=f; x.y*=f; x.z*=f; x.w*=f; }
    s.x+=x.x; s.y+=x.y; s.z+=x.z; s.w+=x.w;
    q.x+=x.x*x.x; q.y+=x.y*x.y; q.z+=x.z*x.z; q.w+=x.w*x.w;
  }
  float* p = part + (long)blockIdx.x*2048;
  st4(&p[c], s);
  st4(&p[1024+c], q);
}

__global__ __launch_bounds__(256)
void colstats_reduce(const float* __restrict__ in, float* __restrict__ out,
                     int nslab, int chunk)
{
  const int idx = blockIdx.x*256 + threadIdx.x;    // 0..2047
  const int s0 = blockIdx.y*chunk;
  const int s1 = min(nslab, s0+chunk);
  float a0=0.f, a1=0.f, a2=0.f, a3=0.f;
  int s = s0;
  for (; s+4 <= s1; s += 4){
    a0 += in[(long)s*2048+idx];
    a1 += in[(long)(s+1)*2048+idx];
    a2 += in[(long)(s+2)*2048+idx];
    a3 += in[(long)(s+3)*2048+idx];
  }
  for (; s < s1; ++s) a0 += in[(long)s*2048+idx];
  out[(long)blockIdx.y*2048 + idx] = (a0+a1)+(a2+a3);
}

// BN apply; sums the final nslab stat-slabs inline (L2-resident), then
// per-thread scale/shift (same arithmetic as reference BN).
__global__ __launch_bounds__(256)
void bn_apply_bf16(const float* __restrict__ X, const float* __restrict__ fr,
                   const float* __restrict__ part, int nslab, float invN,
                   const float* __restrict__ gamma,
                   const float* __restrict__ beta, int relu, u16* __restrict__ out)
{
  const long i = ((long)blockIdx.x*256 + threadIdx.x)*4;
  const int d = (int)(i & 1023);
  float4 s = make_float4(0,0,0,0), qq = make_float4(0,0,0,0);
  for (int sl=0; sl<nslab; ++sl){
    const float4 a = ld4(&part[(long)sl*2048 + d]);
    const float4 b = ld4(&part[(long)sl*2048 + 1024 + d]);
    s.x+=a.x; s.y+=a.y; s.z+=a.z; s.w+=a.w;
    qq.x+=b.x; qq.y+=b.y; qq.z+=b.z; qq.w+=b.w;
  }
  const float4 gm = ld4(&gamma[d]);
  const float4 bt = ld4(&beta[d]);
  float4 sc, sh;
  { const float m=s.x*invN, v=qq.x*invN-m*m; sc.x=gm.x*rsqrtf(v+1e-5f); sh.x=bt.x-m*sc.x; }
  { const float m=s.y*invN, v=qq.y*invN-m*m; sc.y=gm.y*rsqrtf(v+1e-5f); sh.y=bt.y-m*sc.y; }
  { const float m=s.z*invN, v=qq.z*invN-m*m; sc.z=gm.z*rsqrtf(v+1e-5f); sh.z=bt.z-m*sc.z; }
  { const float m=s.w*invN, v=qq.w*invN-m*m; sc.w=gm.w*rsqrtf(v+1e-5f); sh.w=bt.w-m*sc.w; }
  float4 x = ld4(&X[i]);
  if (fr){ const float f = fr[(int)((i>>10)%10)]; x.x*=f; x.y*=f; x.z*=f; x.w*=f; }
  x.x = x.x*sc.x + sh.x; x.y = x.y*sc.y + sh.y;
  x.z = x.z*sc.z + sh.z; x.w = x.w*sc.w + sh.w;
  if (relu){ x.x=fmaxf(x.x,0.f); x.y=fmaxf(x.y,0.f); x.z=fmaxf(x.z,0.f); x.w=fmaxf(x.w,0.f); }
  uint2 o; o.x = pk(x.x,x.y); o.y = pk(x.z,x.w);
  *reinterpret_cast<uint2*>(&out[i]) = o;
}

__device__ __forceinline__ float blockSum256(float v, float* sh4){
  #pragma unroll
  for (int m=32; m; m>>=1) v += __shfl_xor(v, m, 64);
  const int w = threadIdx.x >> 6;
  if ((threadIdx.x & 63) == 0) sh4[w] = v;
  __syncthreads();
  return sh4[0]+sh4[1]+sh4[2]+sh4[3];
}

// text rows L2-normalized -> bf16; rows [400,512) zero-padded.
__global__ __launch_bounds__(256)
void rownorm_bf16(const float* __restrict__ X, u16* __restrict__ out)
{
  __shared__ float sh4[4];
  const int row = blockIdx.x;
  const int d = threadIdx.x*4;
  if (row >= 400){ *reinterpret_cast<uint2*>(&out[(long)row*1024 + d]) = make_uint2(0,0); return; }
  const long base = (long)row*1024 + d;
  const float4 x = ld4(&X[base]);
  const float ss = x.x*x.x + x.y*x.y + x.z*x.z + x.w*x.w;
  const float rn = rsqrtf(blockSum256(ss, sh4));
  uint2 o; o.x = pk(x.x*rn, x.y*rn); o.y = pk(x.z*rn, x.w*rn);
  *reinterpret_cast<uint2*>(&out[base]) = o;
}

// img = t + 0.4*feat (t = 0.6*relu(y3+bv2), bf16 from GEMM3 epilogue);
// L2-normalize per (b,v) row; bf16 out.
__global__ __launch_bounds__(256)
void mix_norm_bf16(const u16* __restrict__ T3, const float* __restrict__ feat,
                   u16* __restrict__ outp)
{
  __shared__ float sh4[4];
  const int m = blockIdx.x;            // 0..5119 = b*10+v
  const long base = (long)m*1024;
  const int d = threadIdx.x*4;
  const uint2 tv = *reinterpret_cast<const uint2*>(&T3[base+d]);
  const float4 f  = ld4(&feat[base+d]);
  float4 img;
  img.x = bf2f((u16)(tv.x&0xffff))   + 0.4f*f.x;
  img.y = bf2f((u16)(tv.x>>16))      + 0.4f*f.y;
  img.z = bf2f((u16)(tv.y&0xffff))   + 0.4f*f.z;
  img.w = bf2f((u16)(tv.y>>16))      + 0.4f*f.w;
  const float ss = img.x*img.x + img.y*img.y + img.z*img.z + img.w*img.w;
  const float rn = rsqrtf(blockSum256(ss, sh4));
  uint2 o; o.x = pk(img.x*rn, img.y*rn); o.y = pk(img.z*rn, img.w*rn);
  *reinterpret_cast<uint2*>(&outp[base+d]) = o;
}

// ------------------------------ Sinkhorn -----------------------------------
// 1 wave per block; sim = 2 split-K slabs summed on load; per-problem local
// convergence (wave-sum |dr| <= 0.25), check every 2nd iter; emits logits.
__global__ __launch_bounds__(64)
void sinkhorn_solve(const float* __restrict__ sim, const float* __restrict__ lsp,
                    float* __restrict__ out)
{
  const int n = blockIdx.x*64 + threadIdx.x;     // 0..51199
  const int b = n / 100, c = n % 100;
  float S[10][4], Km[10][4];
  #pragma unroll
  for (int v=0; v<10; ++v){
    const long off = (long)(b*10+v)*512 + c*4;
    const float4 a0 = ld4(&sim[off]);
    const float4 a1 = ld4(&sim[2621440L + off]);
    S[v][0]=a0.x+a1.x; S[v][1]=a0.y+a1.y; S[v][2]=a0.z+a1.z; S[v][3]=a0.w+a1.w;
    #pragma unroll
    for (int p=0;p<4;++p) Km[v][p] = expf((S[v][p]-1.f)*100.f);
  }
  float r[10], cc[4];
  #pragma unroll
  for (int v=0;v<10;++v) r[v]=1.f;
  #pragma unroll
  for (int p=0;p<4;++p) cc[p]=1.f;
  for (int j=0; j<1000; ++j){
    float lerr = 0.f;
    #pragma unroll
    for (int v=0;v<10;++v){
      const float s = Km[v][0]*cc[0]+Km[v][1]*cc[1]+Km[v][2]*cc[2]+Km[v][3]*cc[3];
      const float rn = __fdividef(0.1f, s);
      lerr += fabsf(rn - r[v]); r[v]=rn;
    }
    #pragma unroll
    for (int p=0;p<4;++p){
      float s = 0.f;
      #pragma unroll
      for (int v=0;v<10;++v) s += Km[v][p]*r[v];
      cc[p] = __fdividef(0.25f, s);
    }
    if (j & 1){
      float w = lerr;
      #pragma unroll
      for (int m=32; m; m>>=1) w += __shfl_xor(w, m, 64);
      if (w <= 0.25f) break;          // uniform across the wave
    }
  }
  float dOT = 0.f;
  #pragma unroll
  for (int v=0;v<10;++v)
    #pragma unroll
    for (int p=0;p<4;++p)
      dOT += r[v]*Km[v][p]*cc[p]*(1.f - S[v][p]);
  out[n] = expf(lsp[0]) * (1.f - dOT);
}

// ---------------------------------------------------------------------------
extern "C" void kernel_launch(void* const* d_in, const int* in_sizes, int n_in,
                              void* d_out, int out_size, void* d_ws, size_t ws_size,
                              hipStream_t stream)
{
  const float* feat  = (const float*)d_in[0];
  const float* textf = (const float*)d_in[1];
  const float* fr    = (const float*)d_in[2];
  const float* bn1g  = (const float*)d_in[3];
  const float* bn1b  = (const float*)d_in[4];
  const float* Wg    = (const float*)d_in[5];
  const float* bg    = (const float*)d_in[6];
  const float* bn2g  = (const float*)d_in[7];
  const float* bn2b  = (const float*)d_in[8];
  const float* Wv1   = (const float*)d_in[9];
  const float* bv1   = (const float*)d_in[10];
  const float* Wv2   = (const float*)d_in[11];
  const float* bv2   = (const float*)d_in[12];
  const float* ls    = (const float*)d_in[13];
  float* out = (float*)d_out;
  char* base = (char*)d_ws;

  // workspace layout (bytes); ws >= 79.3MB (round-2 big tier proven):
  u16*   WB  = (u16*)(base + 0);          // 20.97MB: Wg_bf16, then Wv2_bf16
  u16*   Xb  = (u16*)(base + 20971520);   // 10.49MB: xbn_bf16, later img_bf16
  float* P   = (float*)(base + 31457280); // 33.55MB: slabs / split-K / t / sim
  float* P2  = P + 1310720;               // BN1 stage-2 slabs (8x2048)
  u16*   W1b = (u16*)(base + 65011712);   // 2.10MB: Wv1_bf16
  float* y1  = (float*)(base + 67108864); // 2.10MB
  u16*   Gb  = (u16*)(base + 69206016);   // 1.05MB
  u16*   Hb  = (u16*)(base + 70254592);   // 1.05MB
  u16*   Tb  = (u16*)(base + 71303168);   // 1.05MB (512x1024, rows 400+ zero)
  float* ex  = (float*)(base + 72351744); // stats + BN2 slab area
  float* partY = ex + 4096;               // 512 slabs x 2048 = 4MB (BN2 p1)
  float* partY2= partY + 1048576;         // 8 slabs x 2048 = 64KB

  // --- Wg+Wv1 -> bf16 (one pass) ---
  cvt_w<<<2048,256,0,stream>>>(Wg, Wv1, WB, W1b);

  // --- BN1 + fusion scale -> xbn bf16 (640 -> 8 slabs -> inline in apply) ---
  colstats_p1<<<640,256,0,stream>>>(feat, 8, fr, P);
  colstats_reduce<<<dim3(8,8),256,0,stream>>>(P, P2, 640, 80);
  bn_apply_bf16<<<5120,256,0,stream>>>(feat, fr, P2, 8, 1.f/5120.f,
                                       bn1g, bn1b, 0, Xb);

  // --- GEMM1: y1 = xbn @ Wg^T (512x1024x10240), splitK8, z-affinity ---
  // zPer=1: XCD x owns z-slab x; WS = A 1.31 + B 2.62 MB < 4MB L2.
  gemm_bf16_nt<<<512,256,0,stream>>>(Xb, WB, P, 10240,10240,1024, 1280,
                                     524288L, 1, 8, 8, nullptr, nullptr);
  // fused: split-K reduce + bias + per-row BN2 stats partials
  reduce_f32_stats<<<512,256,0,stream>>>(P, 8, 524288, bg, y1, partY);
  colstats_reduce<<<dim3(8,8),256,0,stream>>>(partY, partY2, 512, 64);
  bn_apply_bf16<<<512,256,0,stream>>>(y1, nullptr, partY2, 8, 1.f/512.f,
                                      bn2g, bn2b, 1, Gb);

  // --- GEMM2: h = relu(g @ Wv1^T + bv1) (512x1024x1024), splitK8, z-aff ---
  gemm_bf16_nt<<<512,256,0,stream>>>(Gb, W1b, P, 1024,1024,1024, 128,
                                     524288L, 1, 8, 8, nullptr, nullptr);
  reduce_bf16<<<512,256,0,stream>>>(P, 8, 524288, bv1, Hb);

  // --- Wv2 -> bf16 (reuses WB; Wg no longer needed) ---
  cvt_bf16<<<2048,256,0,stream>>>(Wv2, WB, 1310720);

  // --- GEMM3: t = 0.6*relu(h @ Wv2^T + bv2) -> bf16, n-affinity ---
  gemm_bf16_nt<<<640,256,0,stream>>>(Hb, WB, nullptr, 1024,1024,10240, 1024,
                                     0L, 2, 80, 8, (u16*)P, bv2);
  mix_norm_bf16<<<5120,256,0,stream>>>((u16*)P, feat, Xb);

  // --- text norm + sim (5120x512x1024), split-K 2 ---
  rownorm_bf16<<<512,256,0,stream>>>(textf, Tb);
  gemm_bf16_nt<<<dim3(4,80,2),256,0,stream>>>(Xb, Tb, P, 1024,1024,512, 512,
                                              2621440L, 0, 0, 0, nullptr, nullptr);

  // --- Sinkhorn + logits (1 wave/block; sums the 2 sim slabs) ---
  sinkhorn_solve<<<800,64,0,stream>>>(P, ls, out);
}

// Round 13
// 164.872 us; speedup vs baseline: 1.0147x; 1.0147x over previous
//
#include <hip/hip_runtime.h>
#include <cstdint>

// ---------------------------------------------------------------------------
// PointCLIP forward on MI355X. GEMMs in bf16 MFMA (fp32 accum), rest fp32.
// Weights pre-converted to bf16 once; XCD-affinity keeps per-XCD GEMM working
// sets inside the private 4MB L2 (per-XCD share of A+B must fit — r10 lesson).
// GEMM1 splitK16/1024 blocks (r12 splitK8 halved TLP: −13µs — reverted).
// GEMM3 fuses bias+relu+0.6x into its epilogue (bf16 out). BN stats via
// atomic-free slab trees; final slab sum inlined into bn_apply.
// Dims fixed per reference: B=512, V=10, D=1024, C=100, P=4.
// ---------------------------------------------------------------------------

typedef unsigned short u16;
typedef __attribute__((ext_vector_type(8))) short bf8v;   // 8 bf16 (4 VGPR)
typedef __attribute__((ext_vector_type(4))) float f4v;    // 4 f32 acc

__device__ __forceinline__ float4 ld4(const float* p){ return *reinterpret_cast<const float4*>(p); }
__device__ __forceinline__ void st4(float* p, float4 v){ *reinterpret_cast<float4*>(p) = v; }
__device__ __forceinline__ u16 f2bf(float x){            // RNE fp32 -> bf16
  uint32_t u = __float_as_uint(x);
  return (u16)((u + 0x7FFFu + ((u>>16)&1u)) >> 16);
}
__device__ __forceinline__ float bf2f(u16 h){ return __uint_as_float(((uint32_t)h)<<16); }
__device__ __forceinline__ uint32_t pk(float a, float b){
  return (uint32_t)f2bf(a) | ((uint32_t)f2bf(b)<<16);
}
__device__ __forceinline__ void glds16(const u16* g, u16* l){
  __builtin_amdgcn_global_load_lds(
      (const __attribute__((address_space(1))) unsigned int*)g,
      (__attribute__((address_space(3))) unsigned int*)l, 16, 0, 0);
}

// ---- block-index remap: 0 plain 3D, 1 z-affinity, 2 n-affinity ------------
__device__ __forceinline__ void remap(int map, int NBX, int NBY,
                                      int& bx, int& by, int& bz)
{
  if (map == 0){ bx = blockIdx.x; by = blockIdx.y; bz = blockIdx.z; return; }
  const int i = blockIdx.x, xcd = i & 7, j = i >> 3;
  if (map == 1){
    const int mnC = NBX*NBY;
    const int zPer = (gridDim.x >> 3) / mnC;
    bz = xcd*zPer + j/mnC;
    const int mn = j % mnC; bx = mn % NBX; by = mn / NBX;
  } else {
    const int nbxPer = NBX >> 3;
    bx = xcd*nbxPer + j % nbxPer; by = j / nbxPer; bz = 0;
  }
}

// ---------------- bf16 NT MFMA GEMM, 64x128 tile ---------------------------
// A: (M,K) bf16 row-major. B: (N,K) bf16 row-major. C fp32 ldc, split-K slab.
// If OB != nullptr: instead write bf16 OB[row][col] = 0.6*relu(acc+bv2[col]).
__global__ __launch_bounds__(256,4)
void gemm_bf16_nt(const u16* __restrict__ A, const u16* __restrict__ B,
                  float* __restrict__ C, int lda, int ldb, int ldc,
                  int kLen, long strideCz, int map, int NBX, int NBY,
                  u16* __restrict__ OB, const float* __restrict__ bv2r)
{
  __shared__ u16 As0[2048], Bs0[4096], As1[2048], Bs1[4096];
  const int tid = threadIdx.x, lane = tid & 63, w = tid >> 6;
  int bx, by, bz; remap(map, NBX, NBY, bx, by, bz);

  const long bm = (long)by*64, bn = (long)bx*128;
  const long kz = (long)bz*kLen;
  C += (long)bz*strideCz;

  const int srow  = lane>>2;
  const int sslot = (lane&3) ^ ((lane>>3)&3);
  const u16* Ag = A + (bm + w*16 + srow)*(long)lda + kz + sslot*8;
  const u16* Bg = B + (bn + w*32 + srow)*(long)ldb + kz + sslot*8;
  const long b16 = 16L*ldb;
  const int woffA = w*512, woffB = w*1024;

  const int fr = lane & 15;
  const int rslot = ((lane>>4) ^ ((lane>>1)&3))*16;
  const int wr = (w>>1)*32, wc = (w&1)*64;

  const f4v zero = {0.f,0.f,0.f,0.f};
  f4v acc[2][4];
  #pragma unroll
  for (int i2=0;i2<2;i2++)
    #pragma unroll
    for (int j2=0;j2<4;j2++) acc[i2][j2]=zero;

  auto STAGE = [&](u16* Al, u16* Bl, int kt){
    glds16(Ag + kt,       Al + woffA);
    glds16(Bg + kt,       Bl + woffB);
    glds16(Bg + kt + b16, Bl + woffB + 512);
  };
  auto COMPUTE = [&](const u16* Asb, const u16* Bsb){
    bf8v af[2], bf[4];
    #pragma unroll
    for (int mi=0; mi<2; ++mi)
      af[mi] = *(const bf8v*)((const char*)Asb + (wr+mi*16+fr)*64 + rslot);
    #pragma unroll
    for (int nj=0; nj<4; ++nj)
      bf[nj] = *(const bf8v*)((const char*)Bsb + (wc+nj*16+fr)*64 + rslot);
    #pragma unroll
    for (int mi=0; mi<2; ++mi)
      #pragma unroll
      for (int nj=0; nj<4; ++nj)
        acc[mi][nj] = __builtin_amdgcn_mfma_f32_16x16x32_bf16(af[mi], bf[nj], acc[mi][nj], 0,0,0);
  };

  STAGE(As0, Bs0, 0);
  __syncthreads();
  int kt = 32;
  for (; kt < kLen - 32; kt += 64){
    STAGE(As1, Bs1, kt);
    COMPUTE(As0, Bs0);
    __syncthreads();
    STAGE(As0, Bs0, kt + 32);
    COMPUTE(As1, Bs1);
    __syncthreads();
  }
  STAGE(As1, Bs1, kt);
  COMPUTE(As0, Bs0);
  __syncthreads();
  COMPUTE(As1, Bs1);

  const int orow = (lane>>4)*4;
  if (OB){
    float bv[4];
    #pragma unroll
    for (int nj=0;nj<4;++nj) bv[nj] = bv2r[bn + wc + fr + nj*16];
    #pragma unroll
    for (int mi=0;mi<2;++mi){
      #pragma unroll
      for (int q=0;q<4;++q){
        const long row = bm + wr + mi*16 + orow + q;
        u16* Orow = OB + row*(long)ldc + bn + wc + fr;
        #pragma unroll
        for (int nj=0;nj<4;++nj)
          Orow[nj*16] = f2bf(0.6f*fmaxf(acc[mi][nj][q] + bv[nj], 0.f));
      }
    }
  } else {
    #pragma unroll
    for (int mi=0;mi<2;++mi){
      #pragma unroll
      for (int q=0;q<4;++q){
        const long row = bm + wr + mi*16 + orow + q;
        float* Crow = C + row*(long)ldc + bn + wc + fr;
        #pragma unroll
        for (int nj=0;nj<4;++nj) Crow[nj*16] = acc[mi][nj][q];
      }
    }
  }
}

// --------------- fp32 -> bf16 weight convert (Wg + Wv1 in one pass) --------
__global__ __launch_bounds__(256)
void cvt_w(const float* __restrict__ Wg, const float* __restrict__ Wv1,
           u16* __restrict__ WB, u16* __restrict__ W1b)
{
  const long NG = 1310720;
  const long NT = NG + 131072;
  for (long i = (long)blockIdx.x*256 + threadIdx.x; i < NT; i += (long)gridDim.x*256){
    const float* src; u16* dst; long k;
    if (i < NG){ src = Wg; dst = WB; k = i; }
    else       { src = Wv1; dst = W1b; k = i - NG; }
    const float4 a = ld4(&src[k*8]), b = ld4(&src[k*8+4]);
    uint4 o;
    o.x = pk(a.x,a.y); o.y = pk(a.z,a.w);
    o.z = pk(b.x,b.y); o.w = pk(b.z,b.w);
    *reinterpret_cast<uint4*>(&dst[k*8]) = o;
  }
}

__global__ __launch_bounds__(256)
void cvt_bf16(const float* __restrict__ in, u16* __restrict__ out, long n8)
{
  for (long i = (long)blockIdx.x*256 + threadIdx.x; i < n8; i += (long)gridDim.x*256){
    const float4 a = ld4(&in[i*8]), b = ld4(&in[i*8+4]);
    uint4 o;
    o.x = pk(a.x,a.y); o.y = pk(a.z,a.w);
    o.z = pk(b.x,b.y); o.w = pk(b.z,b.w);
    *reinterpret_cast<uint4*>(&out[i*8]) = o;
  }
}

// --------- split-K reduce + per-row BN stats partials (block = row) --------
__global__ __launch_bounds__(256)
void reduce_f32_stats(const float* __restrict__ P, int S, int MN,
                      const float* __restrict__ bias, float* __restrict__ out,
                      float* __restrict__ part)
{
  const int b = blockIdx.x, t = threadIdx.x;
  const long i = (long)b*1024 + t*4;
  float4 s = ld4(&P[i]);
  for (int z=1; z<S; ++z){
    const float4 v = ld4(&P[(long)z*MN + i]);
    s.x+=v.x; s.y+=v.y; s.z+=v.z; s.w+=v.w;
  }
  const float4 bb = ld4(&bias[t*4]);
  s.x+=bb.x; s.y+=bb.y; s.z+=bb.z; s.w+=bb.w;
  st4(&out[i], s);
  float* p = part + (long)b*2048;
  st4(&p[t*4], s);
  st4(&p[1024+t*4], make_float4(s.x*s.x, s.y*s.y, s.z*s.z, s.w*s.w));
}

__global__ __launch_bounds__(256)
void reduce_bf16(const float* __restrict__ P, int S, int MN,
                 const float* __restrict__ bias, u16* __restrict__ out)
{
  const long i = ((long)blockIdx.x*256 + threadIdx.x)*4;
  float4 s = ld4(&P[i]);
  for (int z=1; z<S; ++z){
    const float4 v = ld4(&P[(long)z*MN + i]);
    s.x+=v.x; s.y+=v.y; s.z+=v.z; s.w+=v.w;
  }
  const float4 b = ld4(&bias[(int)(i & 1023)]);
  s.x = fmaxf(s.x+b.x,0.f); s.y = fmaxf(s.y+b.y,0.f);
  s.z = fmaxf(s.z+b.z,0.f); s.w = fmaxf(s.w+b.w,0.f);
  uint2 o; o.x = pk(s.x,s.y); o.y = pk(s.z,s.w);
  *reinterpret_cast<uint2*>(&out[i]) = o;
}

// --------------- column stats: multi-stage tree, NO atomics ----------------
__global__ __launch_bounds__(256)
void colstats_p1(const float* __restrict__ X, int rpb, const float* __restrict__ fr,
                 float* __restrict__ part)
{
  const int c = threadIdx.x*4;
  const long r0 = (long)blockIdx.x*rpb;
  float4 s = make_float4(0,0,0,0), q = make_float4(0,0,0,0);
  for (int rr=0; rr<rpb; ++rr){
    const long r = r0+rr;
    float4 x = ld4(&X[r*1024 + c]);
    if (fr){ const float f = fr[(int)(r%10)]; x.x*=f; x.y*=f; x.z*=f; x.w*=f; }
    s.x+=x.x; s.y+=x.y; s.z+=x.z; s.w+=x.w;
    q.x+=x.x*x.x; q.y+=x.y*x.y; q.z+=x.z*x.z; q.w+=x.w*x.w;
  }
  float* p = part + (long)blockIdx.x*2048;
  st4(&p[c], s);
  st4(&p[1024+c], q);
}

__global__ __launch_bounds__(256)
void colstats_reduce(const float* __restrict__ in, float* __restrict__ out,
                     int nslab, int chunk)
{
  const int idx = blockIdx.x*256 + threadIdx.x;    // 0..2047
  const int s0 = blockIdx.y*chunk;
  const int s1 = min(nslab, s0+chunk);
  float a0=0.f, a1=0.f, a2=0.f, a3=0.f;
  int s = s0;
  for (; s+4 <= s1; s += 4){
    a0 += in[(long)s*2048+idx];
    a1 += in[(long)(s+1)*2048+idx];
    a2 += in[(long)(s+2)*2048+idx];
    a3 += in[(long)(s+3)*2048+idx];
  }
  for (; s < s1; ++s) a0 += in[(long)s*2048+idx];
  out[(long)blockIdx.y*2048 + idx] = (a0+a1)+(a2+a3);
}

// BN apply; sums the final nslab stat-slabs inline (L2-resident), then
// per-thread scale/shift (same arithmetic as reference BN).
__global__ __launch_bounds__(256)
void bn_apply_bf16(const float* __restrict__ X, const float* __restrict__ fr,
                   const float* __restrict__ part, int nslab, float invN,
                   const float* __restrict__ gamma,
                   const float* __restrict__ beta, int relu, u16* __restrict__ out)
{
  const long i = ((long)blockIdx.x*256 + threadIdx.x)*4;
  const int d = (int)(i & 1023);
  float4 s = make_float4(0,0,0,0), qq = make_float4(0,0,0,0);
  for (int sl=0; sl<nslab; ++sl){
    const float4 a = ld4(&part[(long)sl*2048 + d]);
    const float4 b = ld4(&part[(long)sl*2048 + 1024 + d]);
    s.x+=a.x; s.y+=a.y; s.z+=a.z; s.w+=a.w;
    qq.x+=b.x; qq.y+=b.y; qq.z+=b.z; qq.w+=b.w;
  }
  const float4 gm = ld4(&gamma[d]);
  const float4 bt = ld4(&beta[d]);
  float4 sc, sh;
  { const float m=s.x*invN, v=qq.x*invN-m*m; sc.x=gm.x*rsqrtf(v+1e-5f); sh.x=bt.x-m*sc.x; }
  { const float m=s.y*invN, v=qq.y*invN-m*m; sc.y=gm.y*rsqrtf(v+1e-5f); sh.y=bt.y-m*sc.y; }
  { const float m=s.z*invN, v=qq.z*invN-m*m; sc.z=gm.z*rsqrtf(v+1e-5f); sh.z=bt.z-m*sc.z; }
  { const float m=s.w*invN, v=qq.w*invN-m*m; sc.w=gm.w*rsqrtf(v+1e-5f); sh.w=bt.w-m*sc.w; }
  float4 x = ld4(&X[i]);
  if (fr){ const float f = fr[(int)((i>>10)%10)]; x.x*=f; x.y*=f; x.z*=f; x.w*=f; }
  x.x = x.x*sc.x + sh.x; x.y = x.y*sc.y + sh.y;
  x.z = x.z*sc.z + sh.z; x.w = x.w*sc.w + sh.w;
  if (relu){ x.x=fmaxf(x.x,0.f); x.y=fmaxf(x.y,0.f); x.z=fmaxf(x.z,0.f); x.w=fmaxf(x.w,0.f); }
  uint2 o; o.x = pk(x.x,x.y); o.y = pk(x.z,x.w);
  *reinterpret_cast<uint2*>(&out[i]) = o;
}

__device__ __forceinline__ float blockSum256(float v, float* sh4){
  #pragma unroll
  for (int m=32; m; m>>=1) v += __shfl_xor(v, m, 64);
  const int w = threadIdx.x >> 6;
  if ((threadIdx.x & 63) == 0) sh4[w] = v;
  __syncthreads();
  return sh4[0]+sh4[1]+sh4[2]+sh4[3];
}

// text rows L2-normalized -> bf16; rows [400,512) zero-padded.
__global__ __launch_bounds__(256)
void rownorm_bf16(const float* __restrict__ X, u16* __restrict__ out)
{
  __shared__ float sh4[4];
  const int row = blockIdx.x;
  const int d = threadIdx.x*4;
  if (row >= 400){ *reinterpret_cast<uint2*>(&out[(long)row*1024 + d]) = make_uint2(0,0); return; }
  const long base = (long)row*1024 + d;
  const float4 x = ld4(&X[base]);
  const float ss = x.x*x.x + x.y*x.y + x.z*x.z + x.w*x.w;
  const float rn = rsqrtf(blockSum256(ss, sh4));
  uint2 o; o.x = pk(x.x*rn, x.y*rn); o.y = pk(x.z*rn, x.w*rn);
  *reinterpret_cast<uint2*>(&out[base]) = o;
}

// img = t + 0.4*feat (t = 0.6*relu(y3+bv2), bf16 from GEMM3 epilogue);
// L2-normalize per (b,v) row; bf16 out.
__global__ __launch_bounds__(256)
void mix_norm_bf16(const u16* __restrict__ T3, const float* __restrict__ feat,
                   u16* __restrict__ outp)
{
  __shared__ float sh4[4];
  const int m = blockIdx.x;            // 0..5119 = b*10+v
  const long base = (long)m*1024;
  const int d = threadIdx.x*4;
  const uint2 tv = *reinterpret_cast<const uint2*>(&T3[base+d]);
  const float4 f  = ld4(&feat[base+d]);
  float4 img;
  img.x = bf2f((u16)(tv.x&0xffff))   + 0.4f*f.x;
  img.y = bf2f((u16)(tv.x>>16))      + 0.4f*f.y;
  img.z = bf2f((u16)(tv.y&0xffff))   + 0.4f*f.z;
  img.w = bf2f((u16)(tv.y>>16))      + 0.4f*f.w;
  const float ss = img.x*img.x + img.y*img.y + img.z*img.z + img.w*img.w;
  const float rn = rsqrtf(blockSum256(ss, sh4));
  uint2 o; o.x = pk(img.x*rn, img.y*rn); o.y = pk(img.z*rn, img.w*rn);
  *reinterpret_cast<uint2*>(&outp[base+d]) = o;
}

// ------------------------------ Sinkhorn -----------------------------------
// 1 wave per block; sim = 2 split-K slabs summed on load; per-problem local
// convergence (wave-sum |dr| <= 0.25), check every 2nd iter; emits logits.
__global__ __launch_bounds__(64)
void sinkhorn_solve(const float* __restrict__ sim, const float* __restrict__ lsp,
                    float* __restrict__ out)
{
  const int n = blockIdx.x*64 + threadIdx.x;     // 0..51199
  const int b = n / 100, c = n % 100;
  float S[10][4], Km[10][4];
  #pragma unroll
  for (int v=0; v<10; ++v){
    const long off = (long)(b*10+v)*512 + c*4;
    const float4 a0 = ld4(&sim[off]);
    const float4 a1 = ld4(&sim[2621440L + off]);
    S[v][0]=a0.x+a1.x; S[v][1]=a0.y+a1.y; S[v][2]=a0.z+a1.z; S[v][3]=a0.w+a1.w;
    #pragma unroll
    for (int p=0;p<4;++p) Km[v][p] = expf((S[v][p]-1.f)*100.f);
  }
  float r[10], cc[4];
  #pragma unroll
  for (int v=0;v<10;++v) r[v]=1.f;
  #pragma unroll
  for (int p=0;p<4;++p) cc[p]=1.f;
  for (int j=0; j<1000; ++j){
    float lerr = 0.f;
    #pragma unroll
    for (int v=0;v<10;++v){
      const float s = Km[v][0]*cc[0]+Km[v][1]*cc[1]+Km[v][2]*cc[2]+Km[v][3]*cc[3];
      const float rn = __fdividef(0.1f, s);
      lerr += fabsf(rn - r[v]); r[v]=rn;
    }
    #pragma unroll
    for (int p=0;p<4;++p){
      float s = 0.f;
      #pragma unroll
      for (int v=0;v<10;++v) s += Km[v][p]*r[v];
      cc[p] = __fdividef(0.25f, s);
    }
    if (j & 1){
      float w = lerr;
      #pragma unroll
      for (int m=32; m; m>>=1) w += __shfl_xor(w, m, 64);
      if (w <= 0.25f) break;          // uniform across the wave
    }
  }
  float dOT = 0.f;
  #pragma unroll
  for (int v=0;v<10;++v)
    #pragma unroll
    for (int p=0;p<4;++p)
      dOT += r[v]*Km[v][p]*cc[p]*(1.f - S[v][p]);
  out[n] = expf(lsp[0]) * (1.f - dOT);
}

// ---------------------------------------------------------------------------
extern "C" void kernel_launch(void* const* d_in, const int* in_sizes, int n_in,
                              void* d_out, int out_size, void* d_ws, size_t ws_size,
                              hipStream_t stream)
{
  const float* feat  = (const float*)d_in[0];
  const float* textf = (const float*)d_in[1];
  const float* fr    = (const float*)d_in[2];
  const float* bn1g  = (const float*)d_in[3];
  const float* bn1b  = (const float*)d_in[4];
  const float* Wg    = (const float*)d_in[5];
  const float* bg    = (const float*)d_in[6];
  const float* bn2g  = (const float*)d_in[7];
  const float* bn2b  = (const float*)d_in[8];
  const float* Wv1   = (const float*)d_in[9];
  const float* bv1   = (const float*)d_in[10];
  const float* Wv2   = (const float*)d_in[11];
  const float* bv2   = (const float*)d_in[12];
  const float* ls    = (const float*)d_in[13];
  float* out = (float*)d_out;
  char* base = (char*)d_ws;

  // workspace layout (bytes); ws >= 79.3MB (round-2 big tier proven):
  u16*   WB  = (u16*)(base + 0);          // 20.97MB: Wg_bf16, then Wv2_bf16
  u16*   Xb  = (u16*)(base + 20971520);   // 10.49MB: xbn_bf16, later img_bf16
  float* P   = (float*)(base + 31457280); // 33.55MB: slabs / split-K / t / sim
  float* P2  = P + 1310720;               // BN1 stage-2 slabs (8x2048)
  u16*   W1b = (u16*)(base + 65011712);   // 2.10MB: Wv1_bf16
  float* y1  = (float*)(base + 67108864); // 2.10MB
  u16*   Gb  = (u16*)(base + 69206016);   // 1.05MB
  u16*   Hb  = (u16*)(base + 70254592);   // 1.05MB
  u16*   Tb  = (u16*)(base + 71303168);   // 1.05MB (512x1024, rows 400+ zero)
  float* ex  = (float*)(base + 72351744); // stats + BN2 slab area
  float* partY = ex + 4096;               // 512 slabs x 2048 = 4MB (BN2 p1)
  float* partY2= partY + 1048576;         // 8 slabs x 2048 = 64KB

  // --- Wg+Wv1 -> bf16 (one pass) ---
  cvt_w<<<2048,256,0,stream>>>(Wg, Wv1, WB, W1b);

  // --- BN1 + fusion scale -> xbn bf16 (640 -> 8 slabs -> inline in apply) ---
  colstats_p1<<<640,256,0,stream>>>(feat, 8, fr, P);
  colstats_reduce<<<dim3(8,8),256,0,stream>>>(P, P2, 640, 80);
  bn_apply_bf16<<<5120,256,0,stream>>>(feat, fr, P2, 8, 1.f/5120.f,
                                       bn1g, bn1b, 0, Xb);

  // --- GEMM1: y1 = xbn @ Wg^T (512x1024x10240), splitK16, z-affinity ---
  // REVERTED to r9/r11 config: 1024 blocks, kLen 640, zPer=2.
  // per-XCD share (A 10.5 + B 21)/8 = 3.9MB < 4MB L2.
  gemm_bf16_nt<<<1024,256,0,stream>>>(Xb, WB, P, 10240,10240,1024, 640,
                                      524288L, 1, 8, 8, nullptr, nullptr);
  // fused: split-K reduce + bias + per-row BN2 stats partials
  reduce_f32_stats<<<512,256,0,stream>>>(P, 16, 524288, bg, y1, partY);
  colstats_reduce<<<dim3(8,8),256,0,stream>>>(partY, partY2, 512, 64);
  bn_apply_bf16<<<512,256,0,stream>>>(y1, nullptr, partY2, 8, 1.f/512.f,
                                      bn2g, bn2b, 1, Gb);

  // --- GEMM2: h = relu(g @ Wv1^T + bv1) (512x1024x1024), splitK8, z-aff ---
  gemm_bf16_nt<<<512,256,0,stream>>>(Gb, W1b, P, 1024,1024,1024, 128,
                                     524288L, 1, 8, 8, nullptr, nullptr);
  reduce_bf16<<<512,256,0,stream>>>(P, 8, 524288, bv1, Hb);

  // --- Wv2 -> bf16 (reuses WB; Wg no longer needed) ---
  cvt_bf16<<<2048,256,0,stream>>>(Wv2, WB, 1310720);

  // --- GEMM3: t = 0.6*relu(h @ Wv2^T + bv2) -> bf16, n-affinity ---
  gemm_bf16_nt<<<640,256,0,stream>>>(Hb, WB, nullptr, 1024,1024,10240, 1024,
                                     0L, 2, 80, 8, (u16*)P, bv2);
  mix_norm_bf16<<<5120,256,0,stream>>>((u16*)P, feat, Xb);

  // --- text norm + sim (5120x512x1024), split-K 2 ---
  rownorm_bf16<<<512,256,0,stream>>>(textf, Tb);
  gemm_bf16_nt<<<dim3(4,80,2),256,0,stream>>>(Xb, Tb, P, 1024,1024,512, 512,
                                              2621440L, 0, 0, 0, nullptr, nullptr);

  // --- Sinkhorn + logits (1 wave/block; sums the 2 sim slabs) ---
  sinkhorn_solve<<<800,64,0,stream>>>(P, ls, out);
}

// Round 14
// 157.796 us; speedup vs baseline: 1.0602x; 1.0448x over previous
//
#include <hip/hip_runtime.h>
#include <cstdint>

// ---------------------------------------------------------------------------
// PointCLIP forward on MI355X. GEMMs in bf16 MFMA (fp32 accum), rest fp32.
// Weights pre-converted to bf16 once; XCD-affinity keeps per-XCD GEMM working
// sets inside the private 4MB L2. GEMM3 fuses bias+relu+0.6x (bf16 out).
// BN stats via atomic-free slab trees ending in a SINGLE stats buffer
// (r12/r13 lesson: inline multi-slab sums in the 5120-block apply pass cost
// 335MB of L2 reads ≈ +10µs; the extra 8-block reduce stage is ~2µs).
// Dims fixed per reference: B=512, V=10, D=1024, C=100, P=4.
// ---------------------------------------------------------------------------

typedef unsigned short u16;
typedef __attribute__((ext_vector_type(8))) short bf8v;   // 8 bf16 (4 VGPR)
typedef __attribute__((ext_vector_type(4))) float f4v;    // 4 f32 acc

__device__ __forceinline__ float4 ld4(const float* p){ return *reinterpret_cast<const float4*>(p); }
__device__ __forceinline__ void st4(float* p, float4 v){ *reinterpret_cast<float4*>(p) = v; }
__device__ __forceinline__ u16 f2bf(float x){            // RNE fp32 -> bf16
  uint32_t u = __float_as_uint(x);
  return (u16)((u + 0x7FFFu + ((u>>16)&1u)) >> 16);
}
__device__ __forceinline__ float bf2f(u16 h){ return __uint_as_float(((uint32_t)h)<<16); }
__device__ __forceinline__ uint32_t pk(float a, float b){
  return (uint32_t)f2bf(a) | ((uint32_t)f2bf(b)<<16);
}
__device__ __forceinline__ void glds16(const u16* g, u16* l){
  __builtin_amdgcn_global_load_lds(
      (const __attribute__((address_space(1))) unsigned int*)g,
      (__attribute__((address_space(3))) unsigned int*)l, 16, 0, 0);
}

// ---- block-index remap: 0 plain 3D, 1 z-affinity, 2 n-affinity ------------
__device__ __forceinline__ void remap(int map, int NBX, int NBY,
                                      int& bx, int& by, int& bz)
{
  if (map == 0){ bx = blockIdx.x; by = blockIdx.y; bz = blockIdx.z; return; }
  const int i = blockIdx.x, xcd = i & 7, j = i >> 3;
  if (map == 1){
    const int mnC = NBX*NBY;
    const int zPer = (gridDim.x >> 3) / mnC;
    bz = xcd*zPer + j/mnC;
    const int mn = j % mnC; bx = mn % NBX; by = mn / NBX;
  } else {
    const int nbxPer = NBX >> 3;
    bx = xcd*nbxPer + j % nbxPer; by = j / nbxPer; bz = 0;
  }
}

// ---------------- bf16 NT MFMA GEMM, 64x128 tile ---------------------------
// A: (M,K) bf16 row-major. B: (N,K) bf16 row-major. C fp32 ldc, split-K slab.
// If OB != nullptr: instead write bf16 OB[row][col] = 0.6*relu(acc+bv2[col]).
__global__ __launch_bounds__(256,4)
void gemm_bf16_nt(const u16* __restrict__ A, const u16* __restrict__ B,
                  float* __restrict__ C, int lda, int ldb, int ldc,
                  int kLen, long strideCz, int map, int NBX, int NBY,
                  u16* __restrict__ OB, const float* __restrict__ bv2r)
{
  __shared__ u16 As0[2048], Bs0[4096], As1[2048], Bs1[4096];
  const int tid = threadIdx.x, lane = tid & 63, w = tid >> 6;
  int bx, by, bz; remap(map, NBX, NBY, bx, by, bz);

  const long bm = (long)by*64, bn = (long)bx*128;
  const long kz = (long)bz*kLen;
  C += (long)bz*strideCz;

  const int srow  = lane>>2;
  const int sslot = (lane&3) ^ ((lane>>3)&3);
  const u16* Ag = A + (bm + w*16 + srow)*(long)lda + kz + sslot*8;
  const u16* Bg = B + (bn + w*32 + srow)*(long)ldb + kz + sslot*8;
  const long b16 = 16L*ldb;
  const int woffA = w*512, woffB = w*1024;

  const int fr = lane & 15;
  const int rslot = ((lane>>4) ^ ((lane>>1)&3))*16;
  const int wr = (w>>1)*32, wc = (w&1)*64;

  const f4v zero = {0.f,0.f,0.f,0.f};
  f4v acc[2][4];
  #pragma unroll
  for (int i2=0;i2<2;i2++)
    #pragma unroll
    for (int j2=0;j2<4;j2++) acc[i2][j2]=zero;

  auto STAGE = [&](u16* Al, u16* Bl, int kt){
    glds16(Ag + kt,       Al + woffA);
    glds16(Bg + kt,       Bl + woffB);
    glds16(Bg + kt + b16, Bl + woffB + 512);
  };
  auto COMPUTE = [&](const u16* Asb, const u16* Bsb){
    bf8v af[2], bf[4];
    #pragma unroll
    for (int mi=0; mi<2; ++mi)
      af[mi] = *(const bf8v*)((const char*)Asb + (wr+mi*16+fr)*64 + rslot);
    #pragma unroll
    for (int nj=0; nj<4; ++nj)
      bf[nj] = *(const bf8v*)((const char*)Bsb + (wc+nj*16+fr)*64 + rslot);
    #pragma unroll
    for (int mi=0; mi<2; ++mi)
      #pragma unroll
      for (int nj=0; nj<4; ++nj)
        acc[mi][nj] = __builtin_amdgcn_mfma_f32_16x16x32_bf16(af[mi], bf[nj], acc[mi][nj], 0,0,0);
  };

  STAGE(As0, Bs0, 0);
  __syncthreads();
  int kt = 32;
  for (; kt < kLen - 32; kt += 64){
    STAGE(As1, Bs1, kt);
    COMPUTE(As0, Bs0);
    __syncthreads();
    STAGE(As0, Bs0, kt + 32);
    COMPUTE(As1, Bs1);
    __syncthreads();
  }
  STAGE(As1, Bs1, kt);
  COMPUTE(As0, Bs0);
  __syncthreads();
  COMPUTE(As1, Bs1);

  const int orow = (lane>>4)*4;
  if (OB){
    float bv[4];
    #pragma unroll
    for (int nj=0;nj<4;++nj) bv[nj] = bv2r[bn + wc + fr + nj*16];
    #pragma unroll
    for (int mi=0;mi<2;++mi){
      #pragma unroll
      for (int q=0;q<4;++q){
        const long row = bm + wr + mi*16 + orow + q;
        u16* Orow = OB + row*(long)ldc + bn + wc + fr;
        #pragma unroll
        for (int nj=0;nj<4;++nj)
          Orow[nj*16] = f2bf(0.6f*fmaxf(acc[mi][nj][q] + bv[nj], 0.f));
      }
    }
  } else {
    #pragma unroll
    for (int mi=0;mi<2;++mi){
      #pragma unroll
      for (int q=0;q<4;++q){
        const long row = bm + wr + mi*16 + orow + q;
        float* Crow = C + row*(long)ldc + bn + wc + fr;
        #pragma unroll
        for (int nj=0;nj<4;++nj) Crow[nj*16] = acc[mi][nj][q];
      }
    }
  }
}

// --------------- fp32 -> bf16 weight convert (Wg + Wv1 in one pass) --------
__global__ __launch_bounds__(256)
void cvt_w(const float* __restrict__ Wg, const float* __restrict__ Wv1,
           u16* __restrict__ WB, u16* __restrict__ W1b)
{
  const long NG = 1310720;
  const long NT = NG + 131072;
  for (long i = (long)blockIdx.x*256 + threadIdx.x; i < NT; i += (long)gridDim.x*256){
    const float* src; u16* dst; long k;
    if (i < NG){ src = Wg; dst = WB; k = i; }
    else       { src = Wv1; dst = W1b; k = i - NG; }
    const float4 a = ld4(&src[k*8]), b = ld4(&src[k*8+4]);
    uint4 o;
    o.x = pk(a.x,a.y); o.y = pk(a.z,a.w);
    o.z = pk(b.x,b.y); o.w = pk(b.z,b.w);
    *reinterpret_cast<uint4*>(&dst[k*8]) = o;
  }
}

__global__ __launch_bounds__(256)
void cvt_bf16(const float* __restrict__ in, u16* __restrict__ out, long n8)
{
  for (long i = (long)blockIdx.x*256 + threadIdx.x; i < n8; i += (long)gridDim.x*256){
    const float4 a = ld4(&in[i*8]), b = ld4(&in[i*8+4]);
    uint4 o;
    o.x = pk(a.x,a.y); o.y = pk(a.z,a.w);
    o.z = pk(b.x,b.y); o.w = pk(b.z,b.w);
    *reinterpret_cast<uint4*>(&out[i*8]) = o;
  }
}

// --------- split-K reduce + per-row BN stats partials (block = row) --------
__global__ __launch_bounds__(256)
void reduce_f32_stats(const float* __restrict__ P, int S, int MN,
                      const float* __restrict__ bias, float* __restrict__ out,
                      float* __restrict__ part)
{
  const int b = blockIdx.x, t = threadIdx.x;
  const long i = (long)b*1024 + t*4;
  float4 s = ld4(&P[i]);
  for (int z=1; z<S; ++z){
    const float4 v = ld4(&P[(long)z*MN + i]);
    s.x+=v.x; s.y+=v.y; s.z+=v.z; s.w+=v.w;
  }
  const float4 bb = ld4(&bias[t*4]);
  s.x+=bb.x; s.y+=bb.y; s.z+=bb.z; s.w+=bb.w;
  st4(&out[i], s);
  float* p = part + (long)b*2048;
  st4(&p[t*4], s);
  st4(&p[1024+t*4], make_float4(s.x*s.x, s.y*s.y, s.z*s.z, s.w*s.w));
}

__global__ __launch_bounds__(256)
void reduce_bf16(const float* __restrict__ P, int S, int MN,
                 const float* __restrict__ bias, u16* __restrict__ out)
{
  const long i = ((long)blockIdx.x*256 + threadIdx.x)*4;
  float4 s = ld4(&P[i]);
  for (int z=1; z<S; ++z){
    const float4 v = ld4(&P[(long)z*MN + i]);
    s.x+=v.x; s.y+=v.y; s.z+=v.z; s.w+=v.w;
  }
  const float4 b = ld4(&bias[(int)(i & 1023)]);
  s.x = fmaxf(s.x+b.x,0.f); s.y = fmaxf(s.y+b.y,0.f);
  s.z = fmaxf(s.z+b.z,0.f); s.w = fmaxf(s.w+b.w,0.f);
  uint2 o; o.x = pk(s.x,s.y); o.y = pk(s.z,s.w);
  *reinterpret_cast<uint2*>(&out[i]) = o;
}

// --------------- column stats: multi-stage tree, NO atomics ----------------
__global__ __launch_bounds__(256)
void colstats_p1(const float* __restrict__ X, int rpb, const float* __restrict__ fr,
                 float* __restrict__ part)
{
  const int c = threadIdx.x*4;
  const long r0 = (long)blockIdx.x*rpb;
  float4 s = make_float4(0,0,0,0), q = make_float4(0,0,0,0);
  for (int rr=0; rr<rpb; ++rr){
    const long r = r0+rr;
    float4 x = ld4(&X[r*1024 + c]);
    if (fr){ const float f = fr[(int)(r%10)]; x.x*=f; x.y*=f; x.z*=f; x.w*=f; }
    s.x+=x.x; s.y+=x.y; s.z+=x.z; s.w+=x.w;
    q.x+=x.x*x.x; q.y+=x.y*x.y; q.z+=x.z*x.z; q.w+=x.w*x.w;
  }
  float* p = part + (long)blockIdx.x*2048;
  st4(&p[c], s);
  st4(&p[1024+c], q);
}

__global__ __launch_bounds__(256)
void colstats_reduce(const float* __restrict__ in, float* __restrict__ out,
                     int nslab, int chunk)
{
  const int idx = blockIdx.x*256 + threadIdx.x;    // 0..2047
  const int s0 = blockIdx.y*chunk;
  const int s1 = min(nslab, s0+chunk);
  float a0=0.f, a1=0.f, a2=0.f, a3=0.f;
  int s = s0;
  for (; s+4 <= s1; s += 4){
    a0 += in[(long)s*2048+idx];
    a1 += in[(long)(s+1)*2048+idx];
    a2 += in[(long)(s+2)*2048+idx];
    a3 += in[(long)(s+3)*2048+idx];
  }
  for (; s < s1; ++s) a0 += in[(long)s*2048+idx];
  out[(long)blockIdx.y*2048 + idx] = (a0+a1)+(a2+a3);
}

// BN apply reading a SINGLE stats buffer (sum||sq), 32B/thread.
__global__ __launch_bounds__(256)
void bn_apply_bf16(const float* __restrict__ X, const float* __restrict__ fr,
                   const float* __restrict__ stats, float invN,
                   const float* __restrict__ gamma,
                   const float* __restrict__ beta, int relu, u16* __restrict__ out)
{
  const long i = ((long)blockIdx.x*256 + threadIdx.x)*4;
  const int d = (int)(i & 1023);
  const float4 s  = ld4(&stats[d]);
  const float4 qq = ld4(&stats[1024+d]);
  const float4 gm = ld4(&gamma[d]);
  const float4 bt = ld4(&beta[d]);
  float4 sc, sh;
  { const float m=s.x*invN, v=qq.x*invN-m*m; sc.x=gm.x*rsqrtf(v+1e-5f); sh.x=bt.x-m*sc.x; }
  { const float m=s.y*invN, v=qq.y*invN-m*m; sc.y=gm.y*rsqrtf(v+1e-5f); sh.y=bt.y-m*sc.y; }
  { const float m=s.z*invN, v=qq.z*invN-m*m; sc.z=gm.z*rsqrtf(v+1e-5f); sh.z=bt.z-m*sc.z; }
  { const float m=s.w*invN, v=qq.w*invN-m*m; sc.w=gm.w*rsqrtf(v+1e-5f); sh.w=bt.w-m*sc.w; }
  float4 x = ld4(&X[i]);
  if (fr){ const float f = fr[(int)((i>>10)%10)]; x.x*=f; x.y*=f; x.z*=f; x.w*=f; }
  x.x = x.x*sc.x + sh.x; x.y = x.y*sc.y + sh.y;
  x.z = x.z*sc.z + sh.z; x.w = x.w*sc.w + sh.w;
  if (relu){ x.x=fmaxf(x.x,0.f); x.y=fmaxf(x.y,0.f); x.z=fmaxf(x.z,0.f); x.w=fmaxf(x.w,0.f); }
  uint2 o; o.x = pk(x.x,x.y); o.y = pk(x.z,x.w);
  *reinterpret_cast<uint2*>(&out[i]) = o;
}

__device__ __forceinline__ float blockSum256(float v, float* sh4){
  #pragma unroll
  for (int m=32; m; m>>=1) v += __shfl_xor(v, m, 64);
  const int w = threadIdx.x >> 6;
  if ((threadIdx.x & 63) == 0) sh4[w] = v;
  __syncthreads();
  return sh4[0]+sh4[1]+sh4[2]+sh4[3];
}

// text rows L2-normalized -> bf16; rows [400,512) zero-padded.
__global__ __launch_bounds__(256)
void rownorm_bf16(const float* __restrict__ X, u16* __restrict__ out)
{
  __shared__ float sh4[4];
  const int row = blockIdx.x;
  const int d = threadIdx.x*4;
  if (row >= 400){ *reinterpret_cast<uint2*>(&out[(long)row*1024 + d]) = make_uint2(0,0); return; }
  const long base = (long)row*1024 + d;
  const float4 x = ld4(&X[base]);
  const float ss = x.x*x.x + x.y*x.y + x.z*x.z + x.w*x.w;
  const float rn = rsqrtf(blockSum256(ss, sh4));
  uint2 o; o.x = pk(x.x*rn, x.y*rn); o.y = pk(x.z*rn, x.w*rn);
  *reinterpret_cast<uint2*>(&out[base]) = o;
}

// img = t + 0.4*feat (t = 0.6*relu(y3+bv2), bf16 from GEMM3 epilogue);
// L2-normalize per (b,v) row; bf16 out.
__global__ __launch_bounds__(256)
void mix_norm_bf16(const u16* __restrict__ T3, const float* __restrict__ feat,
                   u16* __restrict__ outp)
{
  __shared__ float sh4[4];
  const int m = blockIdx.x;            // 0..5119 = b*10+v
  const long base = (long)m*1024;
  const int d = threadIdx.x*4;
  const uint2 tv = *reinterpret_cast<const uint2*>(&T3[base+d]);
  const float4 f  = ld4(&feat[base+d]);
  float4 img;
  img.x = bf2f((u16)(tv.x&0xffff))   + 0.4f*f.x;
  img.y = bf2f((u16)(tv.x>>16))      + 0.4f*f.y;
  img.z = bf2f((u16)(tv.y&0xffff))   + 0.4f*f.z;
  img.w = bf2f((u16)(tv.y>>16))      + 0.4f*f.w;
  const float ss = img.x*img.x + img.y*img.y + img.z*img.z + img.w*img.w;
  const float rn = rsqrtf(blockSum256(ss, sh4));
  uint2 o; o.x = pk(img.x*rn, img.y*rn); o.y = pk(img.z*rn, img.w*rn);
  *reinterpret_cast<uint2*>(&outp[base+d]) = o;
}

// ------------------------------ Sinkhorn -----------------------------------
// 1 wave per block; sim = 2 split-K slabs summed on load; per-problem local
// convergence (wave-sum |dr| <= 0.25), check every 2nd iter; emits logits.
__global__ __launch_bounds__(64)
void sinkhorn_solve(const float* __restrict__ sim, const float* __restrict__ lsp,
                    float* __restrict__ out)
{
  const int n = blockIdx.x*64 + threadIdx.x;     // 0..51199
  const int b = n / 100, c = n % 100;
  float S[10][4], Km[10][4];
  #pragma unroll
  for (int v=0; v<10; ++v){
    const long off = (long)(b*10+v)*512 + c*4;
    const float4 a0 = ld4(&sim[off]);
    const float4 a1 = ld4(&sim[2621440L + off]);
    S[v][0]=a0.x+a1.x; S[v][1]=a0.y+a1.y; S[v][2]=a0.z+a1.z; S[v][3]=a0.w+a1.w;
    #pragma unroll
    for (int p=0;p<4;++p) Km[v][p] = expf((S[v][p]-1.f)*100.f);
  }
  float r[10], cc[4];
  #pragma unroll
  for (int v=0;v<10;++v) r[v]=1.f;
  #pragma unroll
  for (int p=0;p<4;++p) cc[p]=1.f;
  for (int j=0; j<1000; ++j){
    float lerr = 0.f;
    #pragma unroll
    for (int v=0;v<10;++v){
      const float s = Km[v][0]*cc[0]+Km[v][1]*cc[1]+Km[v][2]*cc[2]+Km[v][3]*cc[3];
      const float rn = __fdividef(0.1f, s);
      lerr += fabsf(rn - r[v]); r[v]=rn;
    }
    #pragma unroll
    for (int p=0;p<4;++p){
      float s = 0.f;
      #pragma unroll
      for (int v=0;v<10;++v) s += Km[v][p]*r[v];
      cc[p] = __fdividef(0.25f, s);
    }
    if (j & 1){
      float w = lerr;
      #pragma unroll
      for (int m=32; m; m>>=1) w += __shfl_xor(w, m, 64);
      if (w <= 0.25f) break;          // uniform across the wave
    }
  }
  float dOT = 0.f;
  #pragma unroll
  for (int v=0;v<10;++v)
    #pragma unroll
    for (int p=0;p<4;++p)
      dOT += r[v]*Km[v][p]*cc[p]*(1.f - S[v][p]);
  out[n] = expf(lsp[0]) * (1.f - dOT);
}

// ---------------------------------------------------------------------------
extern "C" void kernel_launch(void* const* d_in, const int* in_sizes, int n_in,
                              void* d_out, int out_size, void* d_ws, size_t ws_size,
                              hipStream_t stream)
{
  const float* feat  = (const float*)d_in[0];
  const float* textf = (const float*)d_in[1];
  const float* fr    = (const float*)d_in[2];
  const float* bn1g  = (const float*)d_in[3];
  const float* bn1b  = (const float*)d_in[4];
  const float* Wg    = (const float*)d_in[5];
  const float* bg    = (const float*)d_in[6];
  const float* bn2g  = (const float*)d_in[7];
  const float* bn2b  = (const float*)d_in[8];
  const float* Wv1   = (const float*)d_in[9];
  const float* bv1   = (const float*)d_in[10];
  const float* Wv2   = (const float*)d_in[11];
  const float* bv2   = (const float*)d_in[12];
  const float* ls    = (const float*)d_in[13];
  float* out = (float*)d_out;
  char* base = (char*)d_ws;

  // workspace layout (bytes); ws >= 79.3MB proven (poison fill ~268MB):
  u16*   WB  = (u16*)(base + 0);          // 20.97MB: Wg_bf16, then Wv2_bf16
  u16*   Xb  = (u16*)(base + 20971520);   // 10.49MB: xbn_bf16, later img_bf16
  float* P   = (float*)(base + 31457280); // 33.55MB: slabs / split-K / t / sim
  float* P2  = P + 1310720;               // BN1 stage-2 slabs (8x2048)
  u16*   W1b = (u16*)(base + 65011712);   // 2.10MB: Wv1_bf16
  float* y1  = (float*)(base + 67108864); // 2.10MB
  u16*   Gb  = (u16*)(base + 69206016);   // 1.05MB
  u16*   Hb  = (u16*)(base + 70254592);   // 1.05MB
  u16*   Tb  = (u16*)(base + 71303168);   // 1.05MB (512x1024, rows 400+ zero)
  float* ex  = (float*)(base + 72351744); // stats + BN2 slab area
  float* bn1st=ex, *bn2st=ex+2048;        // each 2048: sum||sq
  float* partY = ex + 4096;               // 512 slabs x 2048 = 4MB (BN2 p1)
  float* partY2= partY + 1048576;         // 8 slabs x 2048 = 64KB

  // --- Wg+Wv1 -> bf16 (one pass) ---
  cvt_w<<<2048,256,0,stream>>>(Wg, Wv1, WB, W1b);

  // --- BN1 + fusion scale -> xbn bf16 (640 -> 8 -> 1 stats) ---
  colstats_p1<<<640,256,0,stream>>>(feat, 8, fr, P);
  colstats_reduce<<<dim3(8,8),256,0,stream>>>(P, P2, 640, 80);
  colstats_reduce<<<dim3(8,1),256,0,stream>>>(P2, bn1st, 8, 8);
  bn_apply_bf16<<<5120,256,0,stream>>>(feat, fr, bn1st, 1.f/5120.f,
                                       bn1g, bn1b, 0, Xb);

  // --- GEMM1: y1 = xbn @ Wg^T (512x1024x10240), splitK16, z-affinity ---
  // per-XCD share (A 10.5 + B 21)/8 = 3.9MB < 4MB L2.
  gemm_bf16_nt<<<1024,256,0,stream>>>(Xb, WB, P, 10240,10240,1024, 640,
                                      524288L, 1, 8, 8, nullptr, nullptr);
  // fused: split-K reduce + bias + per-row BN2 stats partials
  reduce_f32_stats<<<512,256,0,stream>>>(P, 16, 524288, bg, y1, partY);
  colstats_reduce<<<dim3(8,8),256,0,stream>>>(partY, partY2, 512, 64);
  colstats_reduce<<<dim3(8,1),256,0,stream>>>(partY2, bn2st, 8, 8);
  bn_apply_bf16<<<512,256,0,stream>>>(y1, nullptr, bn2st, 1.f/512.f,
                                      bn2g, bn2b, 1, Gb);

  // --- GEMM2: h = relu(g @ Wv1^T + bv1) (512x1024x1024), splitK8, z-aff ---
  gemm_bf16_nt<<<512,256,0,stream>>>(Gb, W1b, P, 1024,1024,1024, 128,
                                     524288L, 1, 8, 8, nullptr, nullptr);
  reduce_bf16<<<512,256,0,stream>>>(P, 8, 524288, bv1, Hb);

  // --- Wv2 -> bf16 (reuses WB; Wg no longer needed) ---
  cvt_bf16<<<2048,256,0,stream>>>(Wv2, WB, 1310720);

  // --- GEMM3: t = 0.6*relu(h @ Wv2^T + bv2) -> bf16, n-affinity ---
  gemm_bf16_nt<<<640,256,0,stream>>>(Hb, WB, nullptr, 1024,1024,10240, 1024,
                                     0L, 2, 80, 8, (u16*)P, bv2);
  mix_norm_bf16<<<5120,256,0,stream>>>((u16*)P, feat, Xb);

  // --- text norm + sim (5120x512x1024), split-K 2 ---
  rownorm_bf16<<<512,256,0,stream>>>(textf, Tb);
  gemm_bf16_nt<<<dim3(4,80,2),256,0,stream>>>(Xb, Tb, P, 1024,1024,512, 512,
                                              2621440L, 0, 0, 0, nullptr, nullptr);

  // --- Sinkhorn + logits (1 wave/block; sums the 2 sim slabs) ---
  sinkhorn_solve<<<800,64,0,stream>>>(P, ls, out);
}

// Round 15
// 151.314 us; speedup vs baseline: 1.1057x; 1.0428x over previous
//
#include <hip/hip_runtime.h>
#include <cstdint>

// ---------------------------------------------------------------------------
// PointCLIP forward on MI355X. Best-of composition: r9 skeleton (proven
// 152.8us) + GEMM3 fused bias/relu/0.6x bf16 epilogue (-21MB round trip)
// + merged Wg/Wv1 convert. GEMMs bf16 MFMA, XCD-affinity L2 residency.
// Dims fixed per reference: B=512, V=10, D=1024, C=100, P=4.
// ---------------------------------------------------------------------------

typedef unsigned short u16;
typedef __attribute__((ext_vector_type(8))) short bf8v;   // 8 bf16 (4 VGPR)
typedef __attribute__((ext_vector_type(4))) float f4v;    // 4 f32 acc

__device__ __forceinline__ float4 ld4(const float* p){ return *reinterpret_cast<const float4*>(p); }
__device__ __forceinline__ void st4(float* p, float4 v){ *reinterpret_cast<float4*>(p) = v; }
__device__ __forceinline__ u16 f2bf(float x){            // RNE fp32 -> bf16
  uint32_t u = __float_as_uint(x);
  return (u16)((u + 0x7FFFu + ((u>>16)&1u)) >> 16);
}
__device__ __forceinline__ float bf2f(u16 h){ return __uint_as_float(((uint32_t)h)<<16); }
__device__ __forceinline__ uint32_t pk(float a, float b){
  return (uint32_t)f2bf(a) | ((uint32_t)f2bf(b)<<16);
}
__device__ __forceinline__ void glds16(const u16* g, u16* l){
  __builtin_amdgcn_global_load_lds(
      (const __attribute__((address_space(1))) unsigned int*)g,
      (__attribute__((address_space(3))) unsigned int*)l, 16, 0, 0);
}

// ---- block-index remap: 0 plain 3D, 1 z-affinity, 2 n-affinity ------------
__device__ __forceinline__ void remap(int map, int NBX, int NBY,
                                      int& bx, int& by, int& bz)
{
  if (map == 0){ bx = blockIdx.x; by = blockIdx.y; bz = blockIdx.z; return; }
  const int i = blockIdx.x, xcd = i & 7, j = i >> 3;
  if (map == 1){
    const int mnC = NBX*NBY;
    const int zPer = (gridDim.x >> 3) / mnC;
    bz = xcd*zPer + j/mnC;
    const int mn = j % mnC; bx = mn % NBX; by = mn / NBX;
  } else {
    const int nbxPer = NBX >> 3;
    bx = xcd*nbxPer + j % nbxPer; by = j / nbxPer; bz = 0;
  }
}

// ---------------- bf16 NT MFMA GEMM, 64x128 tile ---------------------------
// A: (M,K) bf16 row-major. B: (N,K) bf16 row-major. C fp32 ldc, split-K slab.
// If OB != nullptr: instead write bf16 OB[row][col] = 0.6*relu(acc+bv2[col]).
__global__ __launch_bounds__(256,4)
void gemm_bf16_nt(const u16* __restrict__ A, const u16* __restrict__ B,
                  float* __restrict__ C, int lda, int ldb, int ldc,
                  int kLen, long strideCz, int map, int NBX, int NBY,
                  u16* __restrict__ OB, const float* __restrict__ bv2r)
{
  __shared__ u16 As0[2048], Bs0[4096], As1[2048], Bs1[4096];
  const int tid = threadIdx.x, lane = tid & 63, w = tid >> 6;
  int bx, by, bz; remap(map, NBX, NBY, bx, by, bz);

  const long bm = (long)by*64, bn = (long)bx*128;
  const long kz = (long)bz*kLen;
  C += (long)bz*strideCz;

  const int srow  = lane>>2;
  const int sslot = (lane&3) ^ ((lane>>3)&3);
  const u16* Ag = A + (bm + w*16 + srow)*(long)lda + kz + sslot*8;
  const u16* Bg = B + (bn + w*32 + srow)*(long)ldb + kz + sslot*8;
  const long b16 = 16L*ldb;
  const int woffA = w*512, woffB = w*1024;

  const int fr = lane & 15;
  const int rslot = ((lane>>4) ^ ((lane>>1)&3))*16;
  const int wr = (w>>1)*32, wc = (w&1)*64;

  const f4v zero = {0.f,0.f,0.f,0.f};
  f4v acc[2][4];
  #pragma unroll
  for (int i2=0;i2<2;i2++)
    #pragma unroll
    for (int j2=0;j2<4;j2++) acc[i2][j2]=zero;

  auto STAGE = [&](u16* Al, u16* Bl, int kt){
    glds16(Ag + kt,       Al + woffA);
    glds16(Bg + kt,       Bl + woffB);
    glds16(Bg + kt + b16, Bl + woffB + 512);
  };
  auto COMPUTE = [&](const u16* Asb, const u16* Bsb){
    bf8v af[2], bf[4];
    #pragma unroll
    for (int mi=0; mi<2; ++mi)
      af[mi] = *(const bf8v*)((const char*)Asb + (wr+mi*16+fr)*64 + rslot);
    #pragma unroll
    for (int nj=0; nj<4; ++nj)
      bf[nj] = *(const bf8v*)((const char*)Bsb + (wc+nj*16+fr)*64 + rslot);
    #pragma unroll
    for (int mi=0; mi<2; ++mi)
      #pragma unroll
      for (int nj=0; nj<4; ++nj)
        acc[mi][nj] = __builtin_amdgcn_mfma_f32_16x16x32_bf16(af[mi], bf[nj], acc[mi][nj], 0,0,0);
  };

  STAGE(As0, Bs0, 0);
  __syncthreads();
  int kt = 32;
  for (; kt < kLen - 32; kt += 64){
    STAGE(As1, Bs1, kt);
    COMPUTE(As0, Bs0);
    __syncthreads();
    STAGE(As0, Bs0, kt + 32);
    COMPUTE(As1, Bs1);
    __syncthreads();
  }
  STAGE(As1, Bs1, kt);
  COMPUTE(As0, Bs0);
  __syncthreads();
  COMPUTE(As1, Bs1);

  const int orow = (lane>>4)*4;
  if (OB){
    float bv[4];
    #pragma unroll
    for (int nj=0;nj<4;++nj) bv[nj] = bv2r[bn + wc + fr + nj*16];
    #pragma unroll
    for (int mi=0;mi<2;++mi){
      #pragma unroll
      for (int q=0;q<4;++q){
        const long row = bm + wr + mi*16 + orow + q;
        u16* Orow = OB + row*(long)ldc + bn + wc + fr;
        #pragma unroll
        for (int nj=0;nj<4;++nj)
          Orow[nj*16] = f2bf(0.6f*fmaxf(acc[mi][nj][q] + bv[nj], 0.f));
      }
    }
  } else {
    #pragma unroll
    for (int mi=0;mi<2;++mi){
      #pragma unroll
      for (int q=0;q<4;++q){
        const long row = bm + wr + mi*16 + orow + q;
        float* Crow = C + row*(long)ldc + bn + wc + fr;
        #pragma unroll
        for (int nj=0;nj<4;++nj) Crow[nj*16] = acc[mi][nj][q];
      }
    }
  }
}

// --------------- fp32 -> bf16 weight convert (Wg + Wv1 in one pass) --------
__global__ __launch_bounds__(256)
void cvt_w(const float* __restrict__ Wg, const float* __restrict__ Wv1,
           u16* __restrict__ WB, u16* __restrict__ W1b)
{
  const long NG = 1310720;
  const long NT = NG + 131072;
  for (long i = (long)blockIdx.x*256 + threadIdx.x; i < NT; i += (long)gridDim.x*256){
    const float* src; u16* dst; long k;
    if (i < NG){ src = Wg; dst = WB; k = i; }
    else       { src = Wv1; dst = W1b; k = i - NG; }
    const float4 a = ld4(&src[k*8]), b = ld4(&src[k*8+4]);
    uint4 o;
    o.x = pk(a.x,a.y); o.y = pk(a.z,a.w);
    o.z = pk(b.x,b.y); o.w = pk(b.z,b.w);
    *reinterpret_cast<uint4*>(&dst[k*8]) = o;
  }
}

__global__ __launch_bounds__(256)
void cvt_bf16(const float* __restrict__ in, u16* __restrict__ out, long n8)
{
  for (long i = (long)blockIdx.x*256 + threadIdx.x; i < n8; i += (long)gridDim.x*256){
    const float4 a = ld4(&in[i*8]), b = ld4(&in[i*8+4]);
    uint4 o;
    o.x = pk(a.x,a.y); o.y = pk(a.z,a.w);
    o.z = pk(b.x,b.y); o.w = pk(b.z,b.w);
    *reinterpret_cast<uint4*>(&out[i*8]) = o;
  }
}

// --------------------- split-K reduce variants -----------------------------
__global__ __launch_bounds__(256)
void reduce_f32(const float* __restrict__ P, int S, int MN,
                const float* __restrict__ bias, float* __restrict__ out)
{
  const long i = ((long)blockIdx.x*256 + threadIdx.x)*4;
  float4 s = ld4(&P[i]);
  for (int z=1; z<S; ++z){
    const float4 v = ld4(&P[(long)z*MN + i]);
    s.x+=v.x; s.y+=v.y; s.z+=v.z; s.w+=v.w;
  }
  const float4 b = ld4(&bias[(int)(i & 1023)]);
  s.x+=b.x; s.y+=b.y; s.z+=b.z; s.w+=b.w;
  st4(&out[i], s);
}

__global__ __launch_bounds__(256)
void reduce_bf16(const float* __restrict__ P, int S, int MN,
                 const float* __restrict__ bias, u16* __restrict__ out)
{
  const long i = ((long)blockIdx.x*256 + threadIdx.x)*4;
  float4 s = ld4(&P[i]);
  for (int z=1; z<S; ++z){
    const float4 v = ld4(&P[(long)z*MN + i]);
    s.x+=v.x; s.y+=v.y; s.z+=v.z; s.w+=v.w;
  }
  const float4 b = ld4(&bias[(int)(i & 1023)]);
  s.x = fmaxf(s.x+b.x,0.f); s.y = fmaxf(s.y+b.y,0.f);
  s.z = fmaxf(s.z+b.z,0.f); s.w = fmaxf(s.w+b.w,0.f);
  uint2 o; o.x = pk(s.x,s.y); o.y = pk(s.z,s.w);
  *reinterpret_cast<uint2*>(&out[i]) = o;
}

// --------------- column stats: multi-stage tree, NO atomics ----------------
__global__ __launch_bounds__(256)
void colstats_p1(const float* __restrict__ X, int rpb, const float* __restrict__ fr,
                 float* __restrict__ part)
{
  const int c = threadIdx.x*4;
  const long r0 = (long)blockIdx.x*rpb;
  float4 s = make_float4(0,0,0,0), q = make_float4(0,0,0,0);
  for (int rr=0; rr<rpb; ++rr){
    const long r = r0+rr;
    float4 x = ld4(&X[r*1024 + c]);
    if (fr){ const float f = fr[(int)(r%10)]; x.x*=f; x.y*=f; x.z*=f; x.w*=f; }
    s.x+=x.x; s.y+=x.y; s.z+=x.z; s.w+=x.w;
    q.x+=x.x*x.x; q.y+=x.y*x.y; q.z+=x.z*x.z; q.w+=x.w*x.w;
  }
  float* p = part + (long)blockIdx.x*2048;
  st4(&p[c], s);
  st4(&p[1024+c], q);
}

__global__ __launch_bounds__(256)
void colstats_reduce(const float* __restrict__ in, float* __restrict__ out,
                     int nslab, int chunk)
{
  const int idx = blockIdx.x*256 + threadIdx.x;    // 0..2047
  const int s0 = blockIdx.y*chunk;
  const int s1 = min(nslab, s0+chunk);
  float a0=0.f, a1=0.f, a2=0.f, a3=0.f;
  int s = s0;
  for (; s+4 <= s1; s += 4){
    a0 += in[(long)s*2048+idx];
    a1 += in[(long)(s+1)*2048+idx];
    a2 += in[(long)(s+2)*2048+idx];
    a3 += in[(long)(s+3)*2048+idx];
  }
  for (; s < s1; ++s) a0 += in[(long)s*2048+idx];
  out[(long)blockIdx.y*2048 + idx] = (a0+a1)+(a2+a3);
}

// BN apply reading a SINGLE stats buffer (sum||sq), 32B/thread.
__global__ __launch_bounds__(256)
void bn_apply_bf16(const float* __restrict__ X, const float* __restrict__ fr,
                   const float* __restrict__ stats, float invN,
                   const float* __restrict__ gamma,
                   const float* __restrict__ beta, int relu, u16* __restrict__ out)
{
  const long i = ((long)blockIdx.x*256 + threadIdx.x)*4;
  const int d = (int)(i & 1023);
  const float4 s  = ld4(&stats[d]);
  const float4 qq = ld4(&stats[1024+d]);
  const float4 gm = ld4(&gamma[d]);
  const float4 bt = ld4(&beta[d]);
  float4 sc, sh;
  { const float m=s.x*invN, v=qq.x*invN-m*m; sc.x=gm.x*rsqrtf(v+1e-5f); sh.x=bt.x-m*sc.x; }
  { const float m=s.y*invN, v=qq.y*invN-m*m; sc.y=gm.y*rsqrtf(v+1e-5f); sh.y=bt.y-m*sc.y; }
  { const float m=s.z*invN, v=qq.z*invN-m*m; sc.z=gm.z*rsqrtf(v+1e-5f); sh.z=bt.z-m*sc.z; }
  { const float m=s.w*invN, v=qq.w*invN-m*m; sc.w=gm.w*rsqrtf(v+1e-5f); sh.w=bt.w-m*sc.w; }
  float4 x = ld4(&X[i]);
  if (fr){ const float f = fr[(int)((i>>10)%10)]; x.x*=f; x.y*=f; x.z*=f; x.w*=f; }
  x.x = x.x*sc.x + sh.x; x.y = x.y*sc.y + sh.y;
  x.z = x.z*sc.z + sh.z; x.w = x.w*sc.w + sh.w;
  if (relu){ x.x=fmaxf(x.x,0.f); x.y=fmaxf(x.y,0.f); x.z=fmaxf(x.z,0.f); x.w=fmaxf(x.w,0.f); }
  uint2 o; o.x = pk(x.x,x.y); o.y = pk(x.z,x.w);
  *reinterpret_cast<uint2*>(&out[i]) = o;
}

__device__ __forceinline__ float blockSum256(float v, float* sh4){
  #pragma unroll
  for (int m=32; m; m>>=1) v += __shfl_xor(v, m, 64);
  const int w = threadIdx.x >> 6;
  if ((threadIdx.x & 63) == 0) sh4[w] = v;
  __syncthreads();
  return sh4[0]+sh4[1]+sh4[2]+sh4[3];
}

// text rows L2-normalized -> bf16; rows [400,512) zero-padded.
__global__ __launch_bounds__(256)
void rownorm_bf16(const float* __restrict__ X, u16* __restrict__ out)
{
  __shared__ float sh4[4];
  const int row = blockIdx.x;
  const int d = threadIdx.x*4;
  if (row >= 400){ *reinterpret_cast<uint2*>(&out[(long)row*1024 + d]) = make_uint2(0,0); return; }
  const long base = (long)row*1024 + d;
  const float4 x = ld4(&X[base]);
  const float ss = x.x*x.x + x.y*x.y + x.z*x.z + x.w*x.w;
  const float rn = rsqrtf(blockSum256(ss, sh4));
  uint2 o; o.x = pk(x.x*rn, x.y*rn); o.y = pk(x.z*rn, x.w*rn);
  *reinterpret_cast<uint2*>(&out[base]) = o;
}

// img = t + 0.4*feat (t = 0.6*relu(y3+bv2), bf16 from GEMM3 epilogue);
// L2-normalize per (b,v) row; bf16 out.
__global__ __launch_bounds__(256)
void mix_norm_bf16(const u16* __restrict__ T3, const float* __restrict__ feat,
                   u16* __restrict__ outp)
{
  __shared__ float sh4[4];
  const int m = blockIdx.x;            // 0..5119 = b*10+v
  const long base = (long)m*1024;
  const int d = threadIdx.x*4;
  const uint2 tv = *reinterpret_cast<const uint2*>(&T3[base+d]);
  const float4 f  = ld4(&feat[base+d]);
  float4 img;
  img.x = bf2f((u16)(tv.x&0xffff))   + 0.4f*f.x;
  img.y = bf2f((u16)(tv.x>>16))      + 0.4f*f.y;
  img.z = bf2f((u16)(tv.y&0xffff))   + 0.4f*f.z;
  img.w = bf2f((u16)(tv.y>>16))      + 0.4f*f.w;
  const float ss = img.x*img.x + img.y*img.y + img.z*img.z + img.w*img.w;
  const float rn = rsqrtf(blockSum256(ss, sh4));
  uint2 o; o.x = pk(img.x*rn, img.y*rn); o.y = pk(img.z*rn, img.w*rn);
  *reinterpret_cast<uint2*>(&outp[base+d]) = o;
}

// ------------------------------ Sinkhorn -----------------------------------
// r9 config: 200 blocks x 256; sim = 2 split-K slabs summed on load; local
// wave convergence (wave-sum |dr| <= 0.25, checked each iter); emits logits.
__global__ __launch_bounds__(256)
void sinkhorn_solve(const float* __restrict__ sim, const float* __restrict__ lsp,
                    float* __restrict__ out)
{
  const int n = blockIdx.x*256 + threadIdx.x;     // 0..51199
  const int b = n / 100, c = n % 100;
  float S[10][4], Km[10][4];
  #pragma unroll
  for (int v=0; v<10; ++v){
    const long off = (long)(b*10+v)*512 + c*4;
    const float4 a0 = ld4(&sim[off]);
    const float4 a1 = ld4(&sim[2621440L + off]);
    S[v][0]=a0.x+a1.x; S[v][1]=a0.y+a1.y; S[v][2]=a0.z+a1.z; S[v][3]=a0.w+a1.w;
    #pragma unroll
    for (int p=0;p<4;++p) Km[v][p] = expf((S[v][p]-1.f)*100.f);
  }
  float r[10], cc[4];
  #pragma unroll
  for (int v=0;v<10;++v) r[v]=1.f;
  #pragma unroll
  for (int p=0;p<4;++p) cc[p]=1.f;
  for (int j=0; j<1000; ++j){
    float lerr = 0.f;
    #pragma unroll
    for (int v=0;v<10;++v){
      const float s = Km[v][0]*cc[0]+Km[v][1]*cc[1]+Km[v][2]*cc[2]+Km[v][3]*cc[3];
      const float rn = __fdividef(0.1f, s);
      lerr += fabsf(rn - r[v]); r[v]=rn;
    }
    #pragma unroll
    for (int p=0;p<4;++p){
      float s = 0.f;
      #pragma unroll
      for (int v=0;v<10;++v) s += Km[v][p]*r[v];
      cc[p] = __fdividef(0.25f, s);
    }
    float w = lerr;
    #pragma unroll
    for (int m=32; m; m>>=1) w += __shfl_xor(w, m, 64);
    if (w <= 0.25f) break;            // uniform across the wave
  }
  float dOT = 0.f;
  #pragma unroll
  for (int v=0;v<10;++v)
    #pragma unroll
    for (int p=0;p<4;++p)
      dOT += r[v]*Km[v][p]*cc[p]*(1.f - S[v][p]);
  out[n] = expf(lsp[0]) * (1.f - dOT);
}

// ---------------------------------------------------------------------------
extern "C" void kernel_launch(void* const* d_in, const int* in_sizes, int n_in,
                              void* d_out, int out_size, void* d_ws, size_t ws_size,
                              hipStream_t stream)
{
  const float* feat  = (const float*)d_in[0];
  const float* textf = (const float*)d_in[1];
  const float* fr    = (const float*)d_in[2];
  const float* bn1g  = (const float*)d_in[3];
  const float* bn1b  = (const float*)d_in[4];
  const float* Wg    = (const float*)d_in[5];
  const float* bg    = (const float*)d_in[6];
  const float* bn2g  = (const float*)d_in[7];
  const float* bn2b  = (const float*)d_in[8];
  const float* Wv1   = (const float*)d_in[9];
  const float* bv1   = (const float*)d_in[10];
  const float* Wv2   = (const float*)d_in[11];
  const float* bv2   = (const float*)d_in[12];
  const float* ls    = (const float*)d_in[13];
  float* out = (float*)d_out;
  char* base = (char*)d_ws;

  // workspace layout (bytes); r9-proven:
  u16*   WB  = (u16*)(base + 0);          // 20.97MB: Wg_bf16, then Wv2_bf16
  u16*   Xb  = (u16*)(base + 20971520);   // 10.49MB: xbn_bf16, later img_bf16
  float* P   = (float*)(base + 31457280); // 33.55MB: slabs / split-K / t / sim
  float* P2  = P + 1310720;               // stage-2 slab area
  u16*   W1b = (u16*)(base + 65011712);   // 2.10MB: Wv1_bf16
  float* y1  = (float*)(base + 67108864); // 2.10MB
  u16*   Gb  = (u16*)(base + 69206016);   // 1.05MB
  u16*   Hb  = (u16*)(base + 70254592);   // 1.05MB
  u16*   Tb  = (u16*)(base + 71303168);   // 1.05MB (512x1024, rows 400+ zero)
  float* ex  = (float*)(base + 72351744); // stats
  float* bn1st=ex, *bn2st=ex+2048;        // each 2048: sum||sq

  // --- Wg+Wv1 -> bf16 (one pass) ---
  cvt_w<<<2048,256,0,stream>>>(Wg, Wv1, WB, W1b);

  // --- BN1 + fusion scale -> xbn bf16 (640 -> 20 -> 1, r9 tree) ---
  colstats_p1<<<640,256,0,stream>>>(feat, 8, fr, P);
  colstats_reduce<<<dim3(8,20),256,0,stream>>>(P, P2, 640, 32);
  colstats_reduce<<<dim3(8,1),256,0,stream>>>(P2, bn1st, 20, 20);
  bn_apply_bf16<<<5120,256,0,stream>>>(feat, fr, bn1st, 1.f/5120.f,
                                       bn1g, bn1b, 0, Xb);

  // --- GEMM1: y1 = xbn @ Wg^T (512x1024x10240), splitK16, z-affinity ---
  // per-XCD share (A 10.5 + B 21)/8 = 3.9MB < 4MB L2.
  gemm_bf16_nt<<<1024,256,0,stream>>>(Xb, WB, P, 10240,10240,1024, 640,
                                      524288L, 1, 8, 8, nullptr, nullptr);
  reduce_f32<<<512,256,0,stream>>>(P, 16, 524288, bg, y1);

  // --- BN2 + relu -> g bf16 (r9 scheme: p1 over y1, 128 -> 8 -> 1) ---
  colstats_p1<<<128,256,0,stream>>>(y1, 4, nullptr, P);
  colstats_reduce<<<dim3(8,8),256,0,stream>>>(P, P2, 128, 16);
  colstats_reduce<<<dim3(8,1),256,0,stream>>>(P2, bn2st, 8, 8);
  bn_apply_bf16<<<512,256,0,stream>>>(y1, nullptr, bn2st, 1.f/512.f,
                                      bn2g, bn2b, 1, Gb);

  // --- GEMM2: h = relu(g @ Wv1^T + bv1) (512x1024x1024), splitK8, z-aff ---
  gemm_bf16_nt<<<512,256,0,stream>>>(Gb, W1b, P, 1024,1024,1024, 128,
                                     524288L, 1, 8, 8, nullptr, nullptr);
  reduce_bf16<<<512,256,0,stream>>>(P, 8, 524288, bv1, Hb);

  // --- Wv2 -> bf16 (reuses WB; Wg no longer needed) ---
  cvt_bf16<<<2048,256,0,stream>>>(Wv2, WB, 1310720);

  // --- GEMM3: t = 0.6*relu(h @ Wv2^T + bv2) -> bf16, n-affinity ---
  gemm_bf16_nt<<<640,256,0,stream>>>(Hb, WB, nullptr, 1024,1024,10240, 1024,
                                     0L, 2, 80, 8, (u16*)P, bv2);
  mix_norm_bf16<<<5120,256,0,stream>>>((u16*)P, feat, Xb);

  // --- text norm + sim (5120x512x1024), split-K 2 ---
  rownorm_bf16<<<512,256,0,stream>>>(textf, Tb);
  gemm_bf16_nt<<<dim3(4,80,2),256,0,stream>>>(Xb, Tb, P, 1024,1024,512, 512,
                                              2621440L, 0, 0, 0, nullptr, nullptr);

  // --- Sinkhorn + logits (r9 config: 200x256) ---
  sinkhorn_solve<<<200,256,0,stream>>>(P, ls, out);
}